// Round 4
// baseline (63.113 us; speedup 1.0000x reference)
//
#include <hip/hip_runtime.h>

typedef _Float16 h16;
typedef __attribute__((ext_vector_type(2))) h16 h2v;
typedef __attribute__((ext_vector_type(8))) h16 h8v;

constexpr int H_ = 60, W_ = 108, HW_ = 6480;

// Workspace byte offsets. Features position-major [pos][128] fp16 (256 B/row).
constexpr unsigned B_F0T  = 0;
constexpr unsigned B_F1T  = 1658880;
constexpr unsigned B_F0L1 = 3317760;   // 30*54
constexpr unsigned B_F0L2 = 3732480;   // 15*27
constexpr unsigned B_F0L3 = 3836160;   // 7*13
constexpr unsigned B_F1L1 = 3859456;
constexpr unsigned B_F1L2 = 4274176;
constexpr unsigned B_F1L3 = 4377856;

// ---------------------------------------------------------------------------
// Transpose [128][6480] f32 -> [6480][128] f16, both maps (blockIdx.y).
__global__ __launch_bounds__(256) void k_transpose(const float* __restrict__ f0,
                                                   const float* __restrict__ f1,
                                                   h16* __restrict__ ws) {
    __shared__ float lds[64 * 129];
    const float* src = blockIdx.y ? f1 : f0;
    h16* dst = (h16*)((char*)ws + (blockIdx.y ? B_F1T : B_F0T));
    const int p0 = blockIdx.x * 64;
    const int t  = threadIdx.x;
    const int pr = t & 63, cr = t >> 6;
    #pragma unroll
    for (int cb = 0; cb < 128; cb += 4) {
        int c = cb + cr, p = p0 + pr;
        if (p < HW_) lds[pr * 129 + c] = src[(size_t)c * HW_ + p];
    }
    __syncthreads();
    const int cw = t & 63, pw = t >> 6;     // cw indexes half2 pairs
    #pragma unroll
    for (int pb = 0; pb < 64; pb += 4) {
        int p = p0 + pb + pw;
        if (p < HW_) {
            float a = lds[(pb + pw) * 129 + 2 * cw];
            float b = lds[(pb + pw) * 129 + 2 * cw + 1];
            h2v v; v.x = (h16)a; v.y = (h16)b;
            ((h2v*)dst)[(size_t)p * 64 + cw] = v;
        }
    }
}

// ---------------------------------------------------------------------------
// One-pass pyramid: every level pooled DIRECTLY from L0 with a 2^l x 2^l
// window (equivalent to iterated 2x2 pooling for these dims). fp32 accum via
// fdot2 with (1,0)/(0,1) selectors. 16 threads (uint4 chunks) per position.
__global__ __launch_bounds__(256) void k_pool_all(h16* __restrict__ wsh) {
    char* wsc = (char*)wsh;
    const int idx = blockIdx.x * 256 + threadIdx.x;
    const int map = blockIdx.y;
    const int work = idx >> 4, q = idx & 15;
    if (work >= 2116) return;
    int lvl, pos, wout; unsigned dst;
    if (work < 1620)      { lvl = 1; pos = work;        wout = 54; dst = map ? B_F1L1 : B_F0L1; }
    else if (work < 2025) { lvl = 2; pos = work - 1620; wout = 27; dst = map ? B_F1L2 : B_F0L2; }
    else                  { lvl = 3; pos = work - 2025; wout = 13; dst = map ? B_F1L3 : B_F0L3; }
    const char* src = wsc + (map ? B_F1T : B_F0T);
    const int y = pos / wout, x = pos - y * wout;
    const int n = 1 << lvl;
    float a[8] = {0, 0, 0, 0, 0, 0, 0, 0};
    h2v e0; e0.x = (h16)1.f; e0.y = (h16)0.f;
    h2v e1; e1.x = (h16)0.f; e1.y = (h16)1.f;
    for (int dy = 0; dy < n; ++dy) {
        const char* rp = src + (unsigned)((y * n + dy) * 108 + x * n) * 256 + q * 16;
        for (int dx = 0; dx < n; ++dx) {
            uint4 u = *(const uint4*)(rp + dx * 256);
            a[0] = __builtin_amdgcn_fdot2(__builtin_bit_cast(h2v, u.x), e0, a[0], false);
            a[1] = __builtin_amdgcn_fdot2(__builtin_bit_cast(h2v, u.x), e1, a[1], false);
            a[2] = __builtin_amdgcn_fdot2(__builtin_bit_cast(h2v, u.y), e0, a[2], false);
            a[3] = __builtin_amdgcn_fdot2(__builtin_bit_cast(h2v, u.y), e1, a[3], false);
            a[4] = __builtin_amdgcn_fdot2(__builtin_bit_cast(h2v, u.z), e0, a[4], false);
            a[5] = __builtin_amdgcn_fdot2(__builtin_bit_cast(h2v, u.z), e1, a[5], false);
            a[6] = __builtin_amdgcn_fdot2(__builtin_bit_cast(h2v, u.w), e0, a[6], false);
            a[7] = __builtin_amdgcn_fdot2(__builtin_bit_cast(h2v, u.w), e1, a[7], false);
        }
    }
    const float s = 1.0f / (float)(n * n);
    h8v o;
    #pragma unroll
    for (int k = 0; k < 8; ++k) o[k] = (h16)(a[k] * s);
    *(h8v*)(wsc + dst + (unsigned)pos * 256 + q * 16) = o;
}

// ---------------------------------------------------------------------------
template <int CTRL>
__device__ __forceinline__ float dpp_add(float x) {
    int y = __builtin_amdgcn_update_dpp(0, __builtin_bit_cast(int, x),
                                        CTRL, 0xF, 0xF, true);
    return x + __builtin_bit_cast(float, y);
}

__device__ __forceinline__ float dot_u4(uint4 u, uint4 s, float acc) {
    acc = __builtin_amdgcn_fdot2(__builtin_bit_cast(h2v, u.x),
                                 __builtin_bit_cast(h2v, s.x), acc, false);
    acc = __builtin_amdgcn_fdot2(__builtin_bit_cast(h2v, u.y),
                                 __builtin_bit_cast(h2v, s.y), acc, false);
    acc = __builtin_amdgcn_fdot2(__builtin_bit_cast(h2v, u.z),
                                 __builtin_bit_cast(h2v, s.z), acc, false);
    acc = __builtin_amdgcn_fdot2(__builtin_bit_cast(h2v, u.w),
                                 __builtin_bit_cast(h2v, s.w), acc, false);
    return acc;
}

// One WAVE per (pixel, dir); block = 4 consecutive pixels, one dir.
// Lane L = (col p = L>>3, chunk ch = L&7). Each lane owns two CONTIGUOUS 16B
// chunks of the 256B row (bytes ch*16 and 128+ch*16) -> every load instr
// covers 1KB dense (16 lines, 4 lanes/line). Row-reduce via 3 DPP adds
// (xor1 quad_perm, xor2 quad_perm, xor7 half-mirror). Output staged in LDS,
// written as 16B/channel.
__global__ __launch_bounds__(256, 4) void k_lookup(const h16* __restrict__ wsh,
                                                   const float* __restrict__ flow0,
                                                   const float* __restrict__ flow1,
                                                   const float* __restrict__ embt,
                                                   float* __restrict__ out) {
    __shared__ float so[196][5];   // [channel][pixel], +1 pad vs 4
    const char* ws = (const char*)wsh;
    const int bid = blockIdx.x;
    const int xcd = bid & 7;
    const int dir = xcd >> 2;                      // XCDs 0-3: dir0, 4-7: dir1
    const int ord = (xcd & 3) * 405 + (bid >> 3);  // contiguous chunk per XCD
    const int pix0 = ord * 4;
    const int t = threadIdx.x;
    const int L = t & 63;
    const int pix = pix0 + (t >> 6);
    const int h = pix / 108, w = pix - h * 108;

    const float e = embt[0];
    const float scale = dir ? 1.0f / (1.0f - e) : 1.0f / e;
    const float* fl = dir ? flow0 : flow1;
    const float cx = (float)w + fl[pix] * scale;
    const float cy = (float)h + fl[HW_ + pix] * scale;

    const int ch = L & 7;        // 16B chunk index
    const int p  = L >> 3;       // window column 0..7

    // source feature chunks (pre-scaled by 1/sqrt(128) in fp16)
    const unsigned sbase = (dir ? B_F1T : B_F0T) + (unsigned)pix * 256;
    uint4 su0 = *(const uint4*)(ws + sbase + ch * 16);
    uint4 su1 = *(const uint4*)(ws + sbase + 128 + ch * 16);
    {
        h8v a = __builtin_bit_cast(h8v, su0), b = __builtin_bit_cast(h8v, su1);
        #pragma unroll
        for (int k = 0; k < 8; ++k) {
            a[k] = a[k] * (h16)0.08838834764831845f;
            b[k] = b[k] * (h16)0.08838834764831845f;
        }
        su0 = __builtin_bit_cast(uint4, a);
        su1 = __builtin_bit_cast(uint4, b);
    }

    constexpr unsigned g0[4] = {B_F1T, B_F1L1, B_F1L2, B_F1L3};
    constexpr unsigned g1[4] = {B_F0T, B_F0L1, B_F0L2, B_F0L3};

    #pragma unroll
    for (int lvl = 0; lvl < 4; ++lvl) {
        const unsigned gbase = dir ? g1[lvl] : g0[lvl];
        const int wl = 108 >> lvl, hl = 60 >> lvl;
        const float inv = (lvl == 0) ? 1.f : (lvl == 1) ? 0.5f : (lvl == 2) ? 0.25f : 0.125f;
        const float cxl = cx * inv, cyl = cy * inv;
        const float bxf = floorf(cxl), byf = floorf(cyl);
        const int bx = (int)bxf, by = (int)byf;
        const int gx = bx - 3 + p;
        const int gxc = min(max(gx, 0), wl - 1);
        const bool colv = (gx >= 0) & (gx < wl);
        const int gyo = by - 3 + ch;                 // row this lane keeps
        const bool ownv = colv & (gyo >= 0) & (gyo < hl);

        const unsigned coloff = gbase + (unsigned)gxc * 256 + (unsigned)ch * 16;
        uint4 u0[8], u1[8];
        #pragma unroll
        for (int j = 0; j < 8; ++j) {
            const int gy = by - 3 + j;
            const int gyc = min(max(gy, 0), hl - 1);
            const unsigned ro = coloff + (unsigned)(gyc * wl) * 256;
            u0[j] = *(const uint4*)(ws + ro);
            u1[j] = *(const uint4*)(ws + ro + 128);
        }

        float dval = 0.0f;
        #pragma unroll
        for (int j = 0; j < 8; ++j) {
            float a0 = dot_u4(u0[j], su0, 0.0f);
            float a1 = dot_u4(u1[j], su1, 0.0f);
            float acc = a0 + a1;
            acc = dpp_add<0xB1>(acc);    // quad_perm [1,0,3,2] = xor1
            acc = dpp_add<0x4E>(acc);    // quad_perm [2,3,0,1] = xor2
            acc = dpp_add<0x141>(acc);   // ROW_HALF_MIRROR   = xor7
            dval = (ch == j) ? acc : dval;
        }
        dval = ownv ? dval : 0.0f;

        // bilinear: output (dyi,dxi) for L<49; tap (row,col) lives in lane 8*col+row
        const int dyi = L / 7, dxi = L - dyi * 7;
        const float fx = cxl - bxf, fy = cyl - byf;
        const float d00 = __shfl(dval, 8 * dxi + dyi);
        const float d01 = __shfl(dval, 8 * dxi + dyi + 8);
        const float d10 = __shfl(dval, 8 * dxi + dyi + 1);
        const float d11 = __shfl(dval, 8 * dxi + dyi + 9);
        const float v = (d00 * (1.0f - fx) + d01 * fx) * (1.0f - fy) +
                        (d10 * (1.0f - fx) + d11 * fx) * fy;
        if (L < 49) so[lvl * 49 + L][t >> 6] = v;
    }
    __syncthreads();

    if (t < 196) {
        float4 o = make_float4(so[t][0], so[t][1], so[t][2], so[t][3]);
        *(float4*)(out + (size_t)(dir * 196 + t) * HW_ + pix0) = o;
    } else if (dir == 0 && t < 200) {
        const int c = t - 196;
        const float* f = (c < 2) ? flow0 + (size_t)c * HW_
                                 : flow1 + (size_t)(c - 2) * HW_;
        *(float4*)(out + (size_t)(392 + c) * HW_ + pix0) = *(const float4*)(f + pix0);
    }
}

// ---------------------------------------------------------------------------
extern "C" void kernel_launch(void* const* d_in, const int* in_sizes, int n_in,
                              void* d_out, int out_size, void* d_ws, size_t ws_size,
                              hipStream_t stream) {
    const float* fmap0 = (const float*)d_in[0];
    const float* fmap1 = (const float*)d_in[1];
    const float* flow0 = (const float*)d_in[2];
    const float* flow1 = (const float*)d_in[3];
    const float* embt  = (const float*)d_in[4];
    h16* ws  = (h16*)d_ws;
    float* out = (float*)d_out;

    k_transpose<<<dim3(102, 2), 256, 0, stream>>>(fmap0, fmap1, ws);
    k_pool_all<<<dim3(133, 2), 256, 0, stream>>>(ws);
    k_lookup<<<dim3(405 * 8), 256, 0, stream>>>(ws, flow0, flow1, embt, out);
}

// Round 5
// 47.549 us; speedup vs baseline: 1.3273x; 1.3273x over previous
//
#include <hip/hip_runtime.h>

typedef _Float16 h16;
typedef __attribute__((ext_vector_type(2))) h16 h2v;
typedef __attribute__((ext_vector_type(8))) h16 h8v;

constexpr int H_ = 60, W_ = 108, HW_ = 6480;

// Workspace byte offsets. Features position-major [pos][128] fp16 (256 B/row).
constexpr unsigned B_F0T  = 0;
constexpr unsigned B_F1T  = 1658880;
constexpr unsigned B_F0L1 = 3317760;   // 30*54
constexpr unsigned B_F0L2 = 3732480;   // 15*27
constexpr unsigned B_F0L3 = 3836160;   // 7*13
constexpr unsigned B_F1L1 = 3859456;
constexpr unsigned B_F1L2 = 4274176;
constexpr unsigned B_F1L3 = 4377856;

// ---------------------------------------------------------------------------
// Transpose [128][6480] f32 -> [6480][128] f16, both maps (blockIdx.y).
__global__ __launch_bounds__(256) void k_transpose(const float* __restrict__ f0,
                                                   const float* __restrict__ f1,
                                                   h16* __restrict__ ws) {
    __shared__ float lds[64 * 129];
    const float* src = blockIdx.y ? f1 : f0;
    h16* dst = (h16*)((char*)ws + (blockIdx.y ? B_F1T : B_F0T));
    const int p0 = blockIdx.x * 64;
    const int t  = threadIdx.x;
    const int pr = t & 63, cr = t >> 6;
    #pragma unroll
    for (int cb = 0; cb < 128; cb += 4) {
        int c = cb + cr, p = p0 + pr;
        if (p < HW_) lds[pr * 129 + c] = src[(size_t)c * HW_ + p];
    }
    __syncthreads();
    const int cw = t & 63, pw = t >> 6;     // cw indexes half2 pairs
    #pragma unroll
    for (int pb = 0; pb < 64; pb += 4) {
        int p = p0 + pb + pw;
        if (p < HW_) {
            float a = lds[(pb + pw) * 129 + 2 * cw];
            float b = lds[(pb + pw) * 129 + 2 * cw + 1];
            h2v v; v.x = (h16)a; v.y = (h16)b;
            ((h2v*)dst)[(size_t)p * 64 + cw] = v;
        }
    }
}

// ---------------------------------------------------------------------------
// Iterated 2x2 avg pool, fp16 position-major, fp32 accumulate. blockIdx.y=map.
// All loads are independent 16B chunks issued together -> latency pipelined.
__global__ __launch_bounds__(256) void k_pool(h16* __restrict__ wsh,
                                              int win, int hout, int wout,
                                              unsigned iA, unsigned oA,
                                              unsigned iB, unsigned oB) {
    char* ws = (char*)wsh;
    const unsigned off_in  = blockIdx.y ? iB : iA;
    const unsigned off_out = blockIdx.y ? oB : oA;
    const int idx = blockIdx.x * 256 + threadIdx.x;
    const int total = hout * wout * 16;
    if (idx >= total) return;
    const int pos = idx >> 4, q = idx & 15;
    const int y = pos / wout, x = pos - y * wout;
    const char* r0 = ws + off_in + (unsigned)(2 * y * win + 2 * x) * 256;
    const char* r2 = ws + off_in + (unsigned)((2 * y + 1) * win + 2 * x) * 256;
    h8v a = *(const h8v*)(r0 + q * 16);
    h8v b = *(const h8v*)(r0 + 256 + q * 16);
    h8v c = *(const h8v*)(r2 + q * 16);
    h8v d = *(const h8v*)(r2 + 256 + q * 16);
    h8v o;
    #pragma unroll
    for (int j = 0; j < 8; ++j)
        o[j] = (h16)((((float)a[j] + (float)b[j]) + ((float)c[j] + (float)d[j])) * 0.25f);
    *(h8v*)(ws + off_out + (unsigned)pos * 256 + q * 16) = o;
}

// ---------------------------------------------------------------------------
template <int CTRL>
__device__ __forceinline__ float dpp_add(float x) {
    int y = __builtin_amdgcn_update_dpp(0, __builtin_bit_cast(int, x),
                                        CTRL, 0xF, 0xF, true);
    return x + __builtin_bit_cast(float, y);
}

__device__ __forceinline__ float dot_u4(uint4 u, uint4 s, float acc) {
    acc = __builtin_amdgcn_fdot2(__builtin_bit_cast(h2v, u.x),
                                 __builtin_bit_cast(h2v, s.x), acc, false);
    acc = __builtin_amdgcn_fdot2(__builtin_bit_cast(h2v, u.y),
                                 __builtin_bit_cast(h2v, s.y), acc, false);
    acc = __builtin_amdgcn_fdot2(__builtin_bit_cast(h2v, u.z),
                                 __builtin_bit_cast(h2v, s.z), acc, false);
    acc = __builtin_amdgcn_fdot2(__builtin_bit_cast(h2v, u.w),
                                 __builtin_bit_cast(h2v, s.w), acc, false);
    return acc;
}

// One WAVE per (pixel, dir); block = 4 consecutive pixels, one dir.
// Lane L = (col p = L>>3, chunk ch = L&7). Each lane owns two CONTIGUOUS 16B
// chunks of the 256B row (bytes ch*16 and 128+ch*16) -> every load instr
// covers 1KB dense (16 full lines). Row-reduce via 3 DPP adds (xor1, xor2,
// half-mirror). Output staged in LDS, written as 16B/channel.
__global__ __launch_bounds__(256, 4) void k_lookup(const h16* __restrict__ wsh,
                                                   const float* __restrict__ flow0,
                                                   const float* __restrict__ flow1,
                                                   const float* __restrict__ embt,
                                                   float* __restrict__ out) {
    __shared__ float so[196][5];   // [channel][pixel], +1 pad vs 4
    const char* ws = (const char*)wsh;
    const int bid = blockIdx.x;
    const int xcd = bid & 7;
    const int dir = xcd >> 2;                      // XCDs 0-3: dir0, 4-7: dir1
    const int ord = (xcd & 3) * 405 + (bid >> 3);  // contiguous chunk per XCD
    const int pix0 = ord * 4;
    const int t = threadIdx.x;
    const int L = t & 63;
    const int pix = pix0 + (t >> 6);
    const int h = pix / 108, w = pix - h * 108;

    const float e = embt[0];
    const float scale = dir ? 1.0f / (1.0f - e) : 1.0f / e;
    const float* fl = dir ? flow0 : flow1;
    const float cx = (float)w + fl[pix] * scale;
    const float cy = (float)h + fl[HW_ + pix] * scale;

    const int ch = L & 7;        // 16B chunk index
    const int p  = L >> 3;       // window column 0..7

    // source feature chunks (pre-scaled by 1/sqrt(128) in fp16)
    const unsigned sbase = (dir ? B_F1T : B_F0T) + (unsigned)pix * 256;
    uint4 su0 = *(const uint4*)(ws + sbase + ch * 16);
    uint4 su1 = *(const uint4*)(ws + sbase + 128 + ch * 16);
    {
        h8v a = __builtin_bit_cast(h8v, su0), b = __builtin_bit_cast(h8v, su1);
        #pragma unroll
        for (int k = 0; k < 8; ++k) {
            a[k] = a[k] * (h16)0.08838834764831845f;
            b[k] = b[k] * (h16)0.08838834764831845f;
        }
        su0 = __builtin_bit_cast(uint4, a);
        su1 = __builtin_bit_cast(uint4, b);
    }

    constexpr unsigned g0[4] = {B_F1T, B_F1L1, B_F1L2, B_F1L3};
    constexpr unsigned g1[4] = {B_F0T, B_F0L1, B_F0L2, B_F0L3};

    #pragma unroll
    for (int lvl = 0; lvl < 4; ++lvl) {
        const unsigned gbase = dir ? g1[lvl] : g0[lvl];
        const int wl = 108 >> lvl, hl = 60 >> lvl;
        const float inv = (lvl == 0) ? 1.f : (lvl == 1) ? 0.5f : (lvl == 2) ? 0.25f : 0.125f;
        const float cxl = cx * inv, cyl = cy * inv;
        const float bxf = floorf(cxl), byf = floorf(cyl);
        const int bx = (int)bxf, by = (int)byf;
        const int gx = bx - 3 + p;
        const int gxc = min(max(gx, 0), wl - 1);
        const bool colv = (gx >= 0) & (gx < wl);
        const int gyo = by - 3 + ch;                 // row this lane keeps
        const bool ownv = colv & (gyo >= 0) & (gyo < hl);

        const unsigned coloff = gbase + (unsigned)gxc * 256 + (unsigned)ch * 16;
        uint4 u0[8], u1[8];
        #pragma unroll
        for (int j = 0; j < 8; ++j) {
            const int gy = by - 3 + j;
            const int gyc = min(max(gy, 0), hl - 1);
            const unsigned ro = coloff + (unsigned)(gyc * wl) * 256;
            u0[j] = *(const uint4*)(ws + ro);
            u1[j] = *(const uint4*)(ws + ro + 128);
        }

        float dval = 0.0f;
        #pragma unroll
        for (int j = 0; j < 8; ++j) {
            float a0 = dot_u4(u0[j], su0, 0.0f);
            float a1 = dot_u4(u1[j], su1, 0.0f);
            float acc = a0 + a1;
            acc = dpp_add<0xB1>(acc);    // quad_perm [1,0,3,2] = xor1
            acc = dpp_add<0x4E>(acc);    // quad_perm [2,3,0,1] = xor2
            acc = dpp_add<0x141>(acc);   // ROW_HALF_MIRROR (uniform 4-groups => xor4)
            dval = (ch == j) ? acc : dval;
        }
        dval = ownv ? dval : 0.0f;

        // bilinear: output (dyi,dxi) for L<49; tap (row,col) lives in lane 8*col+row
        const int dyi = L / 7, dxi = L - dyi * 7;
        const float fx = cxl - bxf, fy = cyl - byf;
        const float d00 = __shfl(dval, 8 * dxi + dyi);
        const float d01 = __shfl(dval, 8 * dxi + dyi + 8);
        const float d10 = __shfl(dval, 8 * dxi + dyi + 1);
        const float d11 = __shfl(dval, 8 * dxi + dyi + 9);
        const float v = (d00 * (1.0f - fx) + d01 * fx) * (1.0f - fy) +
                        (d10 * (1.0f - fx) + d11 * fx) * fy;
        if (L < 49) so[lvl * 49 + L][t >> 6] = v;
    }
    __syncthreads();

    if (t < 196) {
        float4 o = make_float4(so[t][0], so[t][1], so[t][2], so[t][3]);
        *(float4*)(out + (size_t)(dir * 196 + t) * HW_ + pix0) = o;
    } else if (dir == 0 && t < 200) {
        const int c = t - 196;
        const float* f = (c < 2) ? flow0 + (size_t)c * HW_
                                 : flow1 + (size_t)(c - 2) * HW_;
        *(float4*)(out + (size_t)(392 + c) * HW_ + pix0) = *(const float4*)(f + pix0);
    }
}

// ---------------------------------------------------------------------------
extern "C" void kernel_launch(void* const* d_in, const int* in_sizes, int n_in,
                              void* d_out, int out_size, void* d_ws, size_t ws_size,
                              hipStream_t stream) {
    const float* fmap0 = (const float*)d_in[0];
    const float* fmap1 = (const float*)d_in[1];
    const float* flow0 = (const float*)d_in[2];
    const float* flow1 = (const float*)d_in[3];
    const float* embt  = (const float*)d_in[4];
    h16* ws  = (h16*)d_ws;
    float* out = (float*)d_out;

    k_transpose<<<dim3(102, 2), 256, 0, stream>>>(fmap0, fmap1, ws);
    k_pool<<<dim3(102, 2), 256, 0, stream>>>(ws, 108, 30, 54, B_F0T,  B_F0L1, B_F1T,  B_F1L1);
    k_pool<<<dim3(26, 2),  256, 0, stream>>>(ws,  54, 15, 27, B_F0L1, B_F0L2, B_F1L1, B_F1L2);
    k_pool<<<dim3(6, 2),   256, 0, stream>>>(ws,  27,  7, 13, B_F0L2, B_F0L3, B_F1L2, B_F1L3);
    k_lookup<<<dim3(405 * 8), 256, 0, stream>>>(ws, flow0, flow1, embt, out);
}

// Round 6
// 44.615 us; speedup vs baseline: 1.4146x; 1.0658x over previous
//
#include <hip/hip_runtime.h>

typedef _Float16 h16;
typedef __attribute__((ext_vector_type(2))) h16 h2v;
typedef __attribute__((ext_vector_type(8))) h16 h8v;

constexpr int H_ = 60, W_ = 108, HW_ = 6480;

// Workspace byte offsets. Features position-major [pos][128] fp16 (256 B/row).
constexpr unsigned B_F0T  = 0;
constexpr unsigned B_F1T  = 1658880;
constexpr unsigned B_F0L1 = 3317760;   // 30*54
constexpr unsigned B_F0L2 = 3732480;   // 15*27
constexpr unsigned B_F0L3 = 3836160;   // 7*13
constexpr unsigned B_F1L1 = 3859456;
constexpr unsigned B_F1L2 = 4274176;
constexpr unsigned B_F1L3 = 4377856;

// ---------------------------------------------------------------------------
// Transpose [128][6480] f32 -> [6480][128] f16, both maps (blockIdx.y).
__global__ __launch_bounds__(256) void k_transpose(const float* __restrict__ f0,
                                                   const float* __restrict__ f1,
                                                   h16* __restrict__ ws) {
    __shared__ float lds[64 * 129];
    const float* src = blockIdx.y ? f1 : f0;
    h16* dst = (h16*)((char*)ws + (blockIdx.y ? B_F1T : B_F0T));
    const int p0 = blockIdx.x * 64;
    const int t  = threadIdx.x;
    const int pr = t & 63, cr = t >> 6;
    #pragma unroll
    for (int cb = 0; cb < 128; cb += 4) {
        int c = cb + cr, p = p0 + pr;
        if (p < HW_) lds[pr * 129 + c] = src[(size_t)c * HW_ + p];
    }
    __syncthreads();
    const int cw = t & 63, pw = t >> 6;     // cw indexes half2 pairs
    #pragma unroll
    for (int pb = 0; pb < 64; pb += 4) {
        int p = p0 + pb + pw;
        if (p < HW_) {
            float a = lds[(pb + pw) * 129 + 2 * cw];
            float b = lds[(pb + pw) * 129 + 2 * cw + 1];
            h2v v; v.x = (h16)a; v.y = (h16)b;
            ((h2v*)dst)[(size_t)p * 64 + cw] = v;
        }
    }
}

// ---------------------------------------------------------------------------
// Full pyramid in ONE launch. L1 = 2x2 avg; L2 = direct 4x4 of L0; L3 =
// direct 8x8 of L0 (identical to iterated 2x2 under floor semantics).
// All loops static; loads issued in independent batches (latency-pipelined).
// Block-ID ranges select the path so each path is wave-uniform.
__global__ __launch_bounds__(256) void k_pyramid(h16* __restrict__ wsh) {
    char* ws = (char*)wsh;
    const int map = blockIdx.y;
    const unsigned srcB = map ? B_F1T : B_F0T;
    const char* s = ws + srcB;
    const int bid = blockIdx.x;
    const int t = threadIdx.x;

    if (bid < 102) {                    // ---- L1: 2x2, 1620 pos x 16 chunks
        const int idx = bid * 256 + t;
        if (idx >= 1620 * 16) return;
        const int pos = idx >> 4, q = idx & 15;
        const int y = pos / 54, x = pos - y * 54;
        const unsigned r0 = (unsigned)(2 * y * 108 + 2 * x) * 256 + q * 16;
        const unsigned r1 = r0 + 108 * 256;
        h8v a = *(const h8v*)(s + r0);
        h8v b = *(const h8v*)(s + r0 + 256);
        h8v c = *(const h8v*)(s + r1);
        h8v d = *(const h8v*)(s + r1 + 256);
        h8v o;
        #pragma unroll
        for (int k = 0; k < 8; ++k)
            o[k] = (h16)((((float)a[k] + (float)b[k]) + ((float)c[k] + (float)d[k])) * 0.25f);
        *(h8v*)(ws + (map ? B_F1L1 : B_F0L1) + (unsigned)pos * 256 + q * 16) = o;
    } else if (bid < 128) {             // ---- L2: direct 4x4, 405 pos x 16
        const int idx = (bid - 102) * 256 + t;
        if (idx >= 405 * 16) return;
        const int pos = idx >> 4, q = idx & 15;
        const int y = pos / 27, x = pos - y * 27;
        float acc[8] = {};
        #pragma unroll
        for (int dy = 0; dy < 4; ++dy) {
            #pragma unroll
            for (int dx = 0; dx < 4; ++dx) {
                h8v u = *(const h8v*)(s + (unsigned)((4 * y + dy) * 108 + 4 * x + dx) * 256 + q * 16);
                #pragma unroll
                for (int k = 0; k < 8; ++k) acc[k] += (float)u[k];
            }
        }
        h8v o;
        #pragma unroll
        for (int k = 0; k < 8; ++k) o[k] = (h16)(acc[k] * 0.0625f);
        *(h8v*)(ws + (map ? B_F1L2 : B_F0L2) + (unsigned)pos * 256 + q * 16) = o;
    } else {                            // ---- L3: direct 8x8, 1 wave per (pos, half)
        const int idx = (bid - 128) * 256 + t;
        if (idx >= 91 * 128) return;
        const int pos = idx >> 7;
        const int sub = idx & 127;
        const int half = sub >> 6, lane = sub & 63;
        const int j = lane >> 3, qq = (lane & 7) + half * 8;  // row j, chunk qq
        const int y = pos / 13, x = pos - y * 13;
        float acc[8] = {};
        #pragma unroll
        for (int dx = 0; dx < 8; ++dx) {
            h8v u = *(const h8v*)(s + (unsigned)((8 * y + j) * 108 + 8 * x + dx) * 256 + qq * 16);
            #pragma unroll
            for (int k = 0; k < 8; ++k) acc[k] += (float)u[k];
        }
        #pragma unroll
        for (int k = 0; k < 8; ++k) {   // reduce over rows j (lane bits 3..5)
            acc[k] += __shfl_xor(acc[k], 8);
            acc[k] += __shfl_xor(acc[k], 16);
            acc[k] += __shfl_xor(acc[k], 32);
        }
        if (j == 0) {
            h8v o;
            #pragma unroll
            for (int k = 0; k < 8; ++k) o[k] = (h16)(acc[k] * 0.015625f);
            *(h8v*)(ws + (map ? B_F1L3 : B_F0L3) + (unsigned)pos * 256 + qq * 16) = o;
        }
    }
}

// ---------------------------------------------------------------------------
template <int CTRL>
__device__ __forceinline__ float dpp_add(float x) {
    int y = __builtin_amdgcn_update_dpp(0, __builtin_bit_cast(int, x),
                                        CTRL, 0xF, 0xF, true);
    return x + __builtin_bit_cast(float, y);
}

__device__ __forceinline__ float dot_u4(uint4 u, uint4 s, float acc) {
    acc = __builtin_amdgcn_fdot2(__builtin_bit_cast(h2v, u.x),
                                 __builtin_bit_cast(h2v, s.x), acc, false);
    acc = __builtin_amdgcn_fdot2(__builtin_bit_cast(h2v, u.y),
                                 __builtin_bit_cast(h2v, s.y), acc, false);
    acc = __builtin_amdgcn_fdot2(__builtin_bit_cast(h2v, u.z),
                                 __builtin_bit_cast(h2v, s.z), acc, false);
    acc = __builtin_amdgcn_fdot2(__builtin_bit_cast(h2v, u.w),
                                 __builtin_bit_cast(h2v, s.w), acc, false);
    return acc;
}

// One WAVE per (pixel, dir); block = 4 consecutive pixels, one dir.
// Lane L = (col p = L>>3, chunk ch = L&7). Each lane owns two CONTIGUOUS 16B
// chunks of the 256B row (bytes ch*16 and 128+ch*16) -> every load instr
// covers 1KB dense (16 full lines). Row-reduce via 3 DPP adds (xor1, xor2,
// half-mirror). Output staged in LDS, written as 16B/channel.
__global__ __launch_bounds__(256, 4) void k_lookup(const h16* __restrict__ wsh,
                                                   const float* __restrict__ flow0,
                                                   const float* __restrict__ flow1,
                                                   const float* __restrict__ embt,
                                                   float* __restrict__ out) {
    __shared__ float so[196][5];   // [channel][pixel], +1 pad vs 4
    const char* ws = (const char*)wsh;
    const int bid = blockIdx.x;
    const int xcd = bid & 7;
    const int dir = xcd >> 2;                      // XCDs 0-3: dir0, 4-7: dir1
    const int ord = (xcd & 3) * 405 + (bid >> 3);  // contiguous chunk per XCD
    const int pix0 = ord * 4;
    const int t = threadIdx.x;
    const int L = t & 63;
    const int pix = pix0 + (t >> 6);
    const int h = pix / 108, w = pix - h * 108;

    const float e = embt[0];
    const float scale = dir ? 1.0f / (1.0f - e) : 1.0f / e;
    const float* fl = dir ? flow0 : flow1;
    const float cx = (float)w + fl[pix] * scale;
    const float cy = (float)h + fl[HW_ + pix] * scale;

    const int ch = L & 7;        // 16B chunk index
    const int p  = L >> 3;       // window column 0..7

    // source feature chunks (pre-scaled by 1/sqrt(128) in fp16)
    const unsigned sbase = (dir ? B_F1T : B_F0T) + (unsigned)pix * 256;
    uint4 su0 = *(const uint4*)(ws + sbase + ch * 16);
    uint4 su1 = *(const uint4*)(ws + sbase + 128 + ch * 16);
    {
        h8v a = __builtin_bit_cast(h8v, su0), b = __builtin_bit_cast(h8v, su1);
        #pragma unroll
        for (int k = 0; k < 8; ++k) {
            a[k] = a[k] * (h16)0.08838834764831845f;
            b[k] = b[k] * (h16)0.08838834764831845f;
        }
        su0 = __builtin_bit_cast(uint4, a);
        su1 = __builtin_bit_cast(uint4, b);
    }

    constexpr unsigned g0[4] = {B_F1T, B_F1L1, B_F1L2, B_F1L3};
    constexpr unsigned g1[4] = {B_F0T, B_F0L1, B_F0L2, B_F0L3};

    #pragma unroll
    for (int lvl = 0; lvl < 4; ++lvl) {
        const unsigned gbase = dir ? g1[lvl] : g0[lvl];
        const int wl = 108 >> lvl, hl = 60 >> lvl;
        const float inv = (lvl == 0) ? 1.f : (lvl == 1) ? 0.5f : (lvl == 2) ? 0.25f : 0.125f;
        const float cxl = cx * inv, cyl = cy * inv;
        const float bxf = floorf(cxl), byf = floorf(cyl);
        const int bx = (int)bxf, by = (int)byf;
        const int gx = bx - 3 + p;
        const int gxc = min(max(gx, 0), wl - 1);
        const bool colv = (gx >= 0) & (gx < wl);
        const int gyo = by - 3 + ch;                 // row this lane keeps
        const bool ownv = colv & (gyo >= 0) & (gyo < hl);

        const unsigned coloff = gbase + (unsigned)gxc * 256 + (unsigned)ch * 16;
        uint4 u0[8], u1[8];
        #pragma unroll
        for (int j = 0; j < 8; ++j) {
            const int gy = by - 3 + j;
            const int gyc = min(max(gy, 0), hl - 1);
            const unsigned ro = coloff + (unsigned)(gyc * wl) * 256;
            u0[j] = *(const uint4*)(ws + ro);
            u1[j] = *(const uint4*)(ws + ro + 128);
        }

        float dval = 0.0f;
        #pragma unroll
        for (int j = 0; j < 8; ++j) {
            float a0 = dot_u4(u0[j], su0, 0.0f);
            float a1 = dot_u4(u1[j], su1, 0.0f);
            float acc = a0 + a1;
            acc = dpp_add<0xB1>(acc);    // quad_perm xor1
            acc = dpp_add<0x4E>(acc);    // quad_perm xor2
            acc = dpp_add<0x141>(acc);   // ROW_HALF_MIRROR (4-group-uniform => xor4)
            dval = (ch == j) ? acc : dval;
        }
        dval = ownv ? dval : 0.0f;

        // bilinear: output (dyi,dxi) for L<49; tap (row,col) lives in lane 8*col+row
        const int dyi = L / 7, dxi = L - dyi * 7;
        const float fx = cxl - bxf, fy = cyl - byf;
        const float d00 = __shfl(dval, 8 * dxi + dyi);
        const float d01 = __shfl(dval, 8 * dxi + dyi + 8);
        const float d10 = __shfl(dval, 8 * dxi + dyi + 1);
        const float d11 = __shfl(dval, 8 * dxi + dyi + 9);
        const float v = (d00 * (1.0f - fx) + d01 * fx) * (1.0f - fy) +
                        (d10 * (1.0f - fx) + d11 * fx) * fy;
        if (L < 49) so[lvl * 49 + L][t >> 6] = v;
    }
    __syncthreads();

    if (t < 196) {
        float4 o = make_float4(so[t][0], so[t][1], so[t][2], so[t][3]);
        *(float4*)(out + (size_t)(dir * 196 + t) * HW_ + pix0) = o;
    } else if (dir == 0 && t < 200) {
        const int c = t - 196;
        const float* f = (c < 2) ? flow0 + (size_t)c * HW_
                                 : flow1 + (size_t)(c - 2) * HW_;
        *(float4*)(out + (size_t)(392 + c) * HW_ + pix0) = *(const float4*)(f + pix0);
    }
}

// ---------------------------------------------------------------------------
extern "C" void kernel_launch(void* const* d_in, const int* in_sizes, int n_in,
                              void* d_out, int out_size, void* d_ws, size_t ws_size,
                              hipStream_t stream) {
    const float* fmap0 = (const float*)d_in[0];
    const float* fmap1 = (const float*)d_in[1];
    const float* flow0 = (const float*)d_in[2];
    const float* flow1 = (const float*)d_in[3];
    const float* embt  = (const float*)d_in[4];
    h16* ws  = (h16*)d_ws;
    float* out = (float*)d_out;

    k_transpose<<<dim3(102, 2), 256, 0, stream>>>(fmap0, fmap1, ws);
    k_pyramid<<<dim3(174, 2), 256, 0, stream>>>(ws);
    k_lookup<<<dim3(405 * 8), 256, 0, stream>>>(ws, flow0, flow1, embt, out);
}

// Round 7
// 42.063 us; speedup vs baseline: 1.5004x; 1.0607x over previous
//
#include <hip/hip_runtime.h>

typedef _Float16 h16;
typedef __attribute__((ext_vector_type(2))) h16 h2v;
typedef __attribute__((ext_vector_type(8))) h16 h8v;

constexpr int H_ = 60, W_ = 108, HW_ = 6480;

// Workspace byte offsets. Features position-major [pos][128] fp16 (256 B/row).
// All features pre-scaled by 128^-0.25 so every dot carries 1/sqrt(128).
constexpr unsigned B_F0T  = 0;
constexpr unsigned B_F1T  = 1658880;
constexpr unsigned B_F0L1 = 3317760;   // 30*54
constexpr unsigned B_F0L2 = 3732480;   // 15*27
constexpr unsigned B_F0L3 = 3836160;   // 7*13
constexpr unsigned B_F1L1 = 3859456;
constexpr unsigned B_F1L2 = 4274176;
constexpr unsigned B_F1L3 = 4377856;

// ---------------------------------------------------------------------------
// Transpose [128][6480] f32 -> [6480][128] f16 (pre-scaled), both maps.
__global__ __launch_bounds__(256) void k_transpose(const float* __restrict__ f0,
                                                   const float* __restrict__ f1,
                                                   h16* __restrict__ ws) {
    __shared__ float lds[64 * 129];
    const float* src = blockIdx.y ? f1 : f0;
    h16* dst = (h16*)((char*)ws + (blockIdx.y ? B_F1T : B_F0T));
    const int p0 = blockIdx.x * 64;
    const int t  = threadIdx.x;
    const int pr = t & 63, cr = t >> 6;
    #pragma unroll
    for (int cb = 0; cb < 128; cb += 4) {
        int c = cb + cr, p = p0 + pr;
        if (p < HW_) lds[pr * 129 + c] = src[(size_t)c * HW_ + p];
    }
    __syncthreads();
    const float S = 0.29730177875068026f;   // 128^-0.25
    const int cw = t & 63, pw = t >> 6;     // cw indexes half2 pairs
    #pragma unroll
    for (int pb = 0; pb < 64; pb += 4) {
        int p = p0 + pb + pw;
        if (p < HW_) {
            float a = lds[(pb + pw) * 129 + 2 * cw] * S;
            float b = lds[(pb + pw) * 129 + 2 * cw + 1] * S;
            h2v v; v.x = (h16)a; v.y = (h16)b;
            ((h2v*)dst)[(size_t)p * 64 + cw] = v;
        }
    }
}

// ---------------------------------------------------------------------------
// Full pyramid in ONE launch. L1 = 2x2 avg; L2 = direct 4x4 of L0; L3 =
// direct 8x8 of L0 (identical to iterated 2x2 under floor semantics).
__global__ __launch_bounds__(256) void k_pyramid(h16* __restrict__ wsh) {
    char* ws = (char*)wsh;
    const int map = blockIdx.y;
    const char* s = ws + (map ? B_F1T : B_F0T);
    const int bid = blockIdx.x;
    const int t = threadIdx.x;

    if (bid < 102) {                    // ---- L1: 2x2, 1620 pos x 16 chunks
        const int idx = bid * 256 + t;
        if (idx >= 1620 * 16) return;
        const int pos = idx >> 4, q = idx & 15;
        const int y = pos / 54, x = pos - y * 54;
        const unsigned r0 = (unsigned)(2 * y * 108 + 2 * x) * 256 + q * 16;
        const unsigned r1 = r0 + 108 * 256;
        h8v a = *(const h8v*)(s + r0);
        h8v b = *(const h8v*)(s + r0 + 256);
        h8v c = *(const h8v*)(s + r1);
        h8v d = *(const h8v*)(s + r1 + 256);
        h8v o;
        #pragma unroll
        for (int k = 0; k < 8; ++k)
            o[k] = (h16)((((float)a[k] + (float)b[k]) + ((float)c[k] + (float)d[k])) * 0.25f);
        *(h8v*)(ws + (map ? B_F1L1 : B_F0L1) + (unsigned)pos * 256 + q * 16) = o;
    } else if (bid < 128) {             // ---- L2: direct 4x4, 405 pos x 16
        const int idx = (bid - 102) * 256 + t;
        if (idx >= 405 * 16) return;
        const int pos = idx >> 4, q = idx & 15;
        const int y = pos / 27, x = pos - y * 27;
        float acc[8] = {};
        #pragma unroll
        for (int dy = 0; dy < 4; ++dy) {
            #pragma unroll
            for (int dx = 0; dx < 4; ++dx) {
                h8v u = *(const h8v*)(s + (unsigned)((4 * y + dy) * 108 + 4 * x + dx) * 256 + q * 16);
                #pragma unroll
                for (int k = 0; k < 8; ++k) acc[k] += (float)u[k];
            }
        }
        h8v o;
        #pragma unroll
        for (int k = 0; k < 8; ++k) o[k] = (h16)(acc[k] * 0.0625f);
        *(h8v*)(ws + (map ? B_F1L2 : B_F0L2) + (unsigned)pos * 256 + q * 16) = o;
    } else {                            // ---- L3: direct 8x8, 1 wave per (pos, half)
        const int idx = (bid - 128) * 256 + t;
        if (idx >= 91 * 128) return;
        const int pos = idx >> 7;
        const int sub = idx & 127;
        const int half = sub >> 6, lane = sub & 63;
        const int j = lane >> 3, qq = (lane & 7) + half * 8;  // row j, chunk qq
        const int y = pos / 13, x = pos - y * 13;
        float acc[8] = {};
        #pragma unroll
        for (int dx = 0; dx < 8; ++dx) {
            h8v u = *(const h8v*)(s + (unsigned)((8 * y + j) * 108 + 8 * x + dx) * 256 + qq * 16);
            #pragma unroll
            for (int k = 0; k < 8; ++k) acc[k] += (float)u[k];
        }
        #pragma unroll
        for (int k = 0; k < 8; ++k) {   // reduce over rows j (lane bits 3..5)
            acc[k] += __shfl_xor(acc[k], 8);
            acc[k] += __shfl_xor(acc[k], 16);
            acc[k] += __shfl_xor(acc[k], 32);
        }
        if (j == 0) {
            h8v o;
            #pragma unroll
            for (int k = 0; k < 8; ++k) o[k] = (h16)(acc[k] * 0.015625f);
            *(h8v*)(ws + (map ? B_F1L3 : B_F0L3) + (unsigned)pos * 256 + qq * 16) = o;
        }
    }
}

// ---------------------------------------------------------------------------
template <int CTRL>
__device__ __forceinline__ float dpp_add(float x) {
    int y = __builtin_amdgcn_update_dpp(0, __builtin_bit_cast(int, x),
                                        CTRL, 0xF, 0xF, true);
    return x + __builtin_bit_cast(float, y);
}

__device__ __forceinline__ float dot_u4(uint4 u, uint4 s, float acc) {
    acc = __builtin_amdgcn_fdot2(__builtin_bit_cast(h2v, u.x),
                                 __builtin_bit_cast(h2v, s.x), acc, false);
    acc = __builtin_amdgcn_fdot2(__builtin_bit_cast(h2v, u.y),
                                 __builtin_bit_cast(h2v, s.y), acc, false);
    acc = __builtin_amdgcn_fdot2(__builtin_bit_cast(h2v, u.z),
                                 __builtin_bit_cast(h2v, s.z), acc, false);
    acc = __builtin_amdgcn_fdot2(__builtin_bit_cast(h2v, u.w),
                                 __builtin_bit_cast(h2v, s.w), acc, false);
    return acc;
}

// One WAVE per (pixel, dir); block = 4 consecutive pixels, one dir.
// Lane L = (col p = L>>3, chunk ch = L&7): two contiguous 16B chunks per row
// (bytes ch*16 and 128+ch*16) -> each load instr covers 1KB dense.
// Level 3 (whole 23.3KB level) is staged in LDS per block -> 25% fewer
// global line-requests, reads move to the DS pipe (parallel with VMEM).
__global__ __launch_bounds__(256, 4) void k_lookup(const h16* __restrict__ wsh,
                                                   const float* __restrict__ flow0,
                                                   const float* __restrict__ flow1,
                                                   const float* __restrict__ embt,
                                                   float* __restrict__ out) {
    __shared__ float so[196][5];          // [channel][pixel], +1 pad
    __shared__ char l3cache[91 * 256];    // whole level-3 of this dir (23.3 KB)
    const char* ws = (const char*)wsh;
    const int bid = blockIdx.x;
    const int xcd = bid & 7;
    const int dir = xcd >> 2;                      // XCDs 0-3: dir0, 4-7: dir1
    const int ord = (xcd & 3) * 405 + (bid >> 3);  // contiguous chunk per XCD
    const int pix0 = ord * 4;
    const int t = threadIdx.x;
    const int L = t & 63;
    const int pix = pix0 + (t >> 6);
    const int h = pix / 108, w = pix - h * 108;

    // stage level-3 (coalesced; 1456 x 16B chunks over 256 threads)
    {
        const char* l3src = ws + (dir ? B_F0L3 : B_F1L3);
        #pragma unroll
        for (int i = 0; i < 6; ++i) {
            const int c = t + i * 256;
            if (c < 91 * 16)
                ((uint4*)l3cache)[c] = *(const uint4*)(l3src + c * 16);
        }
    }

    const float e = embt[0];
    const float scale = dir ? 1.0f / (1.0f - e) : 1.0f / e;
    const float* fl = dir ? flow0 : flow1;
    const float cx = (float)w + fl[pix] * scale;
    const float cy = (float)h + fl[HW_ + pix] * scale;

    const int ch = L & 7;        // 16B chunk index
    const int p  = L >> 3;       // window column 0..7

    // source feature chunks (already scaled by 128^-0.25 at transpose)
    const unsigned sbase = (dir ? B_F1T : B_F0T) + (unsigned)pix * 256;
    const uint4 su0 = *(const uint4*)(ws + sbase + ch * 16);
    const uint4 su1 = *(const uint4*)(ws + sbase + 128 + ch * 16);

    constexpr unsigned g0[4] = {B_F1T, B_F1L1, B_F1L2, B_F1L3};
    constexpr unsigned g1[4] = {B_F0T, B_F0L1, B_F0L2, B_F0L3};

    __syncthreads();   // l3cache ready

    #pragma unroll
    for (int lvl = 0; lvl < 4; ++lvl) {
        const unsigned gbase = dir ? g1[lvl] : g0[lvl];
        const int wl = 108 >> lvl, hl = 60 >> lvl;
        const float inv = (lvl == 0) ? 1.f : (lvl == 1) ? 0.5f : (lvl == 2) ? 0.25f : 0.125f;
        const float cxl = cx * inv, cyl = cy * inv;
        const float bxf = floorf(cxl), byf = floorf(cyl);
        const int bx = (int)bxf, by = (int)byf;
        const int gx = bx - 3 + p;
        const int gxc = min(max(gx, 0), wl - 1);
        const bool colv = (gx >= 0) & (gx < wl);
        const int gyo = by - 3 + ch;                 // row this lane keeps
        const bool ownv = colv & (gyo >= 0) & (gyo < hl);

        uint4 u0[8], u1[8];
        if (lvl == 3) {                  // LDS path (whole level cached)
            const unsigned co = (unsigned)gxc * 256 + (unsigned)ch * 16;
            #pragma unroll
            for (int j = 0; j < 8; ++j) {
                const int gy = by - 3 + j;
                const int gyc = min(max(gy, 0), hl - 1);
                const unsigned ro = co + (unsigned)(gyc * wl) * 256;
                u0[j] = *(const uint4*)(l3cache + ro);
                u1[j] = *(const uint4*)(l3cache + ro + 128);
            }
        } else {                         // global path
            const unsigned coloff = gbase + (unsigned)gxc * 256 + (unsigned)ch * 16;
            #pragma unroll
            for (int j = 0; j < 8; ++j) {
                const int gy = by - 3 + j;
                const int gyc = min(max(gy, 0), hl - 1);
                const unsigned ro = coloff + (unsigned)(gyc * wl) * 256;
                u0[j] = *(const uint4*)(ws + ro);
                u1[j] = *(const uint4*)(ws + ro + 128);
            }
        }

        float dval = 0.0f;
        #pragma unroll
        for (int j = 0; j < 8; ++j) {
            float a0 = dot_u4(u0[j], su0, 0.0f);
            float a1 = dot_u4(u1[j], su1, 0.0f);
            float acc = a0 + a1;
            acc = dpp_add<0xB1>(acc);    // quad_perm xor1
            acc = dpp_add<0x4E>(acc);    // quad_perm xor2
            acc = dpp_add<0x141>(acc);   // ROW_HALF_MIRROR (4-group-uniform => xor4)
            dval = (ch == j) ? acc : dval;
        }
        dval = ownv ? dval : 0.0f;

        // bilinear: output (dyi,dxi) for L<49; tap (row,col) lives in lane 8*col+row
        const int dyi = L / 7, dxi = L - dyi * 7;
        const float fx = cxl - bxf, fy = cyl - byf;
        const float d00 = __shfl(dval, 8 * dxi + dyi);
        const float d01 = __shfl(dval, 8 * dxi + dyi + 8);
        const float d10 = __shfl(dval, 8 * dxi + dyi + 1);
        const float d11 = __shfl(dval, 8 * dxi + dyi + 9);
        const float v = (d00 * (1.0f - fx) + d01 * fx) * (1.0f - fy) +
                        (d10 * (1.0f - fx) + d11 * fx) * fy;
        if (L < 49) so[lvl * 49 + L][t >> 6] = v;
    }
    __syncthreads();

    if (t < 196) {
        float4 o = make_float4(so[t][0], so[t][1], so[t][2], so[t][3]);
        *(float4*)(out + (size_t)(dir * 196 + t) * HW_ + pix0) = o;
    } else if (dir == 0 && t < 200) {
        const int c = t - 196;
        const float* f = (c < 2) ? flow0 + (size_t)c * HW_
                                 : flow1 + (size_t)(c - 2) * HW_;
        *(float4*)(out + (size_t)(392 + c) * HW_ + pix0) = *(const float4*)(f + pix0);
    }
}

// ---------------------------------------------------------------------------
extern "C" void kernel_launch(void* const* d_in, const int* in_sizes, int n_in,
                              void* d_out, int out_size, void* d_ws, size_t ws_size,
                              hipStream_t stream) {
    const float* fmap0 = (const float*)d_in[0];
    const float* fmap1 = (const float*)d_in[1];
    const float* flow0 = (const float*)d_in[2];
    const float* flow1 = (const float*)d_in[3];
    const float* embt  = (const float*)d_in[4];
    h16* ws  = (h16*)d_ws;
    float* out = (float*)d_out;

    k_transpose<<<dim3(102, 2), 256, 0, stream>>>(fmap0, fmap1, ws);
    k_pyramid<<<dim3(174, 2), 256, 0, stream>>>(ws);
    k_lookup<<<dim3(405 * 8), 256, 0, stream>>>(ws, flow0, flow1, embt, out);
}